// Round 4
// baseline (158.830 us; speedup 1.0000x reference)
//
#include <hip/hip_runtime.h>
#include <math.h>

// InfoNCE (NT-Xent), N=8192, D=128, fp32 in, scalar fp32 out.
// g = normalize(h)*sqrt(5*log2e) quantized to fp8 e4m3; MFMA fp8 Gram with
// exp2 row/col sums; pos + diag terms recomputed exactly in fp32.

constexpr int D = 128;
constexpr float E5 = 148.4131591025766f;   // e^5 (diag of exp(inter))

typedef __attribute__((ext_vector_type(16))) float f32x16;  // 32x32 MFMA acc

__global__ __launch_bounds__(256) void normalize_kernel(
    const float2* __restrict__ h1, const float2* __restrict__ h2,
    unsigned short* __restrict__ g1b, unsigned short* __restrict__ g2b,
    float* __restrict__ d12, float* __restrict__ acc, float* __restrict__ out,
    int N)
{
    const float SC = sqrtf(5.0f * 1.44269504088896340736f);  // sqrt(5*log2e)
    int gid = blockIdx.x * 256 + threadIdx.x;
    if (gid < 4 * N) acc[gid] = 0.f;
    if (gid == 0) out[0] = 0.f;

    int row  = blockIdx.x * 4 + (threadIdx.x >> 6);
    int lane = threadIdx.x & 63;
    float2 u = h1[(size_t)row * 64 + lane];
    float2 w = h2[(size_t)row * 64 + lane];
    float ss1 = u.x * u.x + u.y * u.y;
    float ss2 = w.x * w.x + w.y * w.y;
    float s12 = u.x * w.x + u.y * w.y;
#pragma unroll
    for (int off = 32; off > 0; off >>= 1) {
        ss1 += __shfl_xor(ss1, off, 64);
        ss2 += __shfl_xor(ss2, off, 64);
        s12 += __shfl_xor(s12, off, 64);
    }
    float n1 = fmaxf(sqrtf(ss1), 1e-12f);
    float n2 = fmaxf(sqrtf(ss2), 1e-12f);
    float c1 = SC / n1, c2 = SC / n2;
    int p1 = __builtin_amdgcn_cvt_pk_fp8_f32(u.x * c1, u.y * c1, 0, false);
    int p2 = __builtin_amdgcn_cvt_pk_fp8_f32(w.x * c2, w.y * c2, 0, false);
    g1b[(size_t)row * 64 + lane] = (unsigned short)(p1 & 0xffff);
    g2b[(size_t)row * 64 + lane] = (unsigned short)(p2 & 0xffff);
    if (lane == 0) d12[row] = 5.f * s12 / (n1 * n2);
}

// Gram exp2-sum. z=0: g1.g1 -> r11 ; z=1: g1.g2 -> r12 rows + c12 cols ;
// z=2: g2.g2 -> r22. Block 256 thr (4 waves); 128x128 tile per j-iter; wave
// tile 64x64 = 2 A-strips x 2 B-cols (2x B reuse). A in regs (K=128 fp8 = 32
// VGPRs). Y streams through 16KB LDS, 8B-fragment XOR swizzle (conflict-free
// b64 reads / b128 writes), register prefetch of next tile under compute.
__global__ __launch_bounds__(256, 3) void gram_mfma_kernel(
    const unsigned char* __restrict__ g1b, const unsigned char* __restrict__ g2b,
    float* __restrict__ r11, float* __restrict__ r12,
    float* __restrict__ c12, float* __restrict__ r22,
    int N, int jIters)
{
    const int z = blockIdx.z;
    const unsigned char* X; const unsigned char* Y; float* rrow; bool COLS = false;
    if (z == 0)      { X = g1b; Y = g1b; rrow = r11; }
    else if (z == 1) { X = g1b; Y = g2b; rrow = r12; COLS = true; }
    else             { X = g2b; Y = g2b; rrow = r22; }

    __shared__ long Ys[128 * 16];   // 16 KB: 128 rows x 16 8B-fragments

    const int tx   = threadIdx.x;
    const int wave = tx >> 6, lane = tx & 63;
    const int l32  = lane & 31, lhi = lane >> 5;
    const int wi   = wave >> 1, wj = wave & 1;
    const int iBase = blockIdx.x * 128;

    // A-fragments: a[st][ks], rows iBase + wi*64 + st*32 + l32, k = ks*16+lhi*8
    long a[2][8];
#pragma unroll
    for (int st = 0; st < 2; ++st) {
        const unsigned char* xp =
            X + (size_t)(iBase + wi * 64 + st * 32 + l32) * D + lhi * 8;
#pragma unroll
        for (int ks = 0; ks < 8; ++ks)
            a[st][ks] = *(const long*)(xp + ks * 16);
    }

    float racc0[16], racc1[16];
#pragma unroll
    for (int r = 0; r < 16; ++r) { racc0[r] = 0.f; racc1[r] = 0.f; }

    const int jt0 = blockIdx.y * jIters;

    // prefetch first Y tile: 256 thr x 16 B x 4 = 16 KB
    long2 v[4];
    {
        const long2* yp = (const long2*)(Y + (size_t)(jt0 * 128) * D);
#pragma unroll
        for (int i = 0; i < 4; ++i) v[i] = yp[i * 256 + tx];
    }

    const int j0 = wj * 64 + l32;       // B col for ct=0
    const int j1 = j0 + 32;             // B col for ct=1
    const int sw0 = j0 & 15, sw1 = j1 & 15;   // equal, but keep explicit

    for (int jt = 0; jt < jIters; ++jt) {
        __syncthreads();   // prev iter's ds_reads done
#pragma unroll
        for (int i = 0; i < 4; ++i) {
            int chunk = i * 256 + tx;
            int j = chunk >> 3, c = chunk & 7;
            int f0p = (2 * c) ^ (j & 15);
            int base = f0p & ~1;
            long2 w = v[i];
            if (j & 1) { long t = w.x; w.x = w.y; w.y = t; }
            *(long2*)&Ys[j * 16 + base] = w;
        }
        __syncthreads();

        // prefetch next tile; flies under MFMA + epilogue
        if (jt + 1 < jIters) {
            const long2* yp =
                (const long2*)(Y + (size_t)((jt0 + jt + 1) * 128) * D);
#pragma unroll
            for (int i = 0; i < 4; ++i) v[i] = yp[i * 256 + tx];
        }

        f32x16 acc00, acc01, acc10, acc11;
#pragma unroll
        for (int r = 0; r < 16; ++r) {
            acc00[r] = 0.f; acc01[r] = 0.f; acc10[r] = 0.f; acc11[r] = 0.f;
        }

#pragma unroll
        for (int ks = 0; ks < 8; ++ks) {
            int f = 2 * ks + lhi;
            long b0 = Ys[j0 * 16 + (f ^ sw0)];
            long b1 = Ys[j1 * 16 + (f ^ sw1)];
            acc00 = __builtin_amdgcn_mfma_f32_32x32x16_fp8_fp8(a[0][ks], b0, acc00, 0, 0, 0);
            acc10 = __builtin_amdgcn_mfma_f32_32x32x16_fp8_fp8(a[1][ks], b0, acc10, 0, 0, 0);
            acc01 = __builtin_amdgcn_mfma_f32_32x32x16_fp8_fp8(a[0][ks], b1, acc01, 0, 0, 0);
            acc11 = __builtin_amdgcn_mfma_f32_32x32x16_fp8_fp8(a[1][ks], b1, acc11, 0, 0, 0);
        }

        // epilogue: exp2 + row sums (dots are in log2e units); col sums only z=1
        if (COLS) {
            const int jBase = (jt0 + jt) * 128;
            float cp0 = 0.f, cp1 = 0.f;
#pragma unroll
            for (int r = 0; r < 16; ++r) {
                float e00 = __builtin_amdgcn_exp2f(acc00[r]);
                float e01 = __builtin_amdgcn_exp2f(acc01[r]);
                float e10 = __builtin_amdgcn_exp2f(acc10[r]);
                float e11 = __builtin_amdgcn_exp2f(acc11[r]);
                racc0[r] += e00 + e01;
                racc1[r] += e10 + e11;
                cp0 += e00 + e10;
                cp1 += e01 + e11;
            }
            cp0 += __shfl_xor(cp0, 32, 64);
            cp1 += __shfl_xor(cp1, 32, 64);
            if (lane < 32) {
                atomicAdd(&c12[jBase + j0], cp0);
                atomicAdd(&c12[jBase + j1], cp1);
            }
        } else {
#pragma unroll
            for (int r = 0; r < 16; ++r) {
                racc0[r] += __builtin_amdgcn_exp2f(acc00[r]) +
                            __builtin_amdgcn_exp2f(acc01[r]);
                racc1[r] += __builtin_amdgcn_exp2f(acc10[r]) +
                            __builtin_amdgcn_exp2f(acc11[r]);
            }
        }
    }

    // row sums: reduce over 32 col-lanes; C layout row=(r&3)+8*(r>>2)+4*lhi
#pragma unroll
    for (int r = 0; r < 16; ++r) {
        float s0 = racc0[r], s1 = racc1[r];
#pragma unroll
        for (int off = 1; off < 32; off <<= 1) {
            s0 += __shfl_xor(s0, off, 64);
            s1 += __shfl_xor(s1, off, 64);
        }
        if (l32 == 0) {
            int rowm = (r & 3) + 8 * (r >> 2) + 4 * lhi;
            atomicAdd(&rrow[iBase + wi * 64 + rowm], s0);
            atomicAdd(&rrow[iBase + wi * 64 + 32 + rowm], s1);
        }
    }
}

// loss_i = 0.5*(log(r11+r12-e5) + log(r22+c12-e5)) - d12 ; out = mean
__global__ __launch_bounds__(256) void loss_reduce_kernel(
    const float* __restrict__ r11, const float* __restrict__ r12,
    const float* __restrict__ c12, const float* __restrict__ r22,
    const float* __restrict__ d12, float* __restrict__ out, int N)
{
    __shared__ float sm[256];
    float s = 0.f;
    for (int i = blockIdx.x * 256 + threadIdx.x; i < N; i += gridDim.x * 256) {
        float neg1 = r11[i] + r12[i] - E5;
        float neg2 = r22[i] + c12[i] - E5;
        s += 0.5f * (logf(neg1) + logf(neg2)) - d12[i];
    }
    sm[threadIdx.x] = s;
    __syncthreads();
    for (int w = 128; w > 0; w >>= 1) {
        if (threadIdx.x < w) sm[threadIdx.x] += sm[threadIdx.x + w];
        __syncthreads();
    }
    if (threadIdx.x == 0) atomicAdd(out, sm[0] / (float)N);
}

extern "C" void kernel_launch(void* const* d_in, const int* in_sizes, int n_in,
                              void* d_out, int out_size, void* d_ws, size_t ws_size,
                              hipStream_t stream) {
    const float* h1 = (const float*)d_in[0];
    const float* h2 = (const float*)d_in[1];
    const int N = in_sizes[0] / D;   // 8192

    unsigned char* g1b = (unsigned char*)d_ws;
    unsigned char* g2b = g1b + (size_t)N * D;
    float* acc  = (float*)(g2b + (size_t)N * D);
    float* r11  = acc;
    float* r12  = acc + N;
    float* c12  = acc + 2 * N;
    float* r22  = acc + 3 * N;
    float* d12  = acc + 4 * N;
    float* out  = (float*)d_out;

    normalize_kernel<<<N / 4, 256, 0, stream>>>(
        (const float2*)h1, (const float2*)h2,
        (unsigned short*)g1b, (unsigned short*)g2b, d12, acc, out, N);

    const int JCHUNKS = 8;
    const int jIters  = (N / 128) / JCHUNKS;   // 8 at N=8192
    dim3 grid(N / 128, JCHUNKS, 3);
    gram_mfma_kernel<<<grid, 256, 0, stream>>>(g1b, g2b, r11, r12, c12, r22, N, jIters);

    loss_reduce_kernel<<<32, 256, 0, stream>>>(r11, r12, c12, r22, d12, out, N);
}

// Round 5
// 114.849 us; speedup vs baseline: 1.3830x; 1.3830x over previous
//
#include <hip/hip_runtime.h>
#include <math.h>

// InfoNCE (NT-Xent), N=8192, D=128, fp32 in, scalar fp32 out.
// g = normalize(h)*sqrt(5*log2e) quantized to fp8 e4m3; MFMA fp8 Gram with
// exp2 row/col sums; pos + diag terms recomputed exactly in fp32.
// Symmetric passes (g1.g1, g2.g2) compute only ~half the tiles and emit
// column sums (= transposed row sums) for the off-diagonal tiles.

constexpr int D = 128;
constexpr float E5 = 148.4131591025766f;   // e^5 (diag of exp(inter))

typedef __attribute__((ext_vector_type(16))) float f32x16;  // 32x32 MFMA acc

__global__ __launch_bounds__(256) void normalize_kernel(
    const float2* __restrict__ h1, const float2* __restrict__ h2,
    unsigned short* __restrict__ g1b, unsigned short* __restrict__ g2b,
    float* __restrict__ d12, float* __restrict__ acc, float* __restrict__ out,
    int N)
{
    const float SC = sqrtf(5.0f * 1.44269504088896340736f);  // sqrt(5*log2e)
    int gid = blockIdx.x * 256 + threadIdx.x;
    if (gid < 4 * N) acc[gid] = 0.f;
    if (gid == 0) out[0] = 0.f;

    int row  = blockIdx.x * 4 + (threadIdx.x >> 6);
    int lane = threadIdx.x & 63;
    float2 u = h1[(size_t)row * 64 + lane];
    float2 w = h2[(size_t)row * 64 + lane];
    float ss1 = u.x * u.x + u.y * u.y;
    float ss2 = w.x * w.x + w.y * w.y;
    float s12 = u.x * w.x + u.y * w.y;
#pragma unroll
    for (int off = 32; off > 0; off >>= 1) {
        ss1 += __shfl_xor(ss1, off, 64);
        ss2 += __shfl_xor(ss2, off, 64);
        s12 += __shfl_xor(s12, off, 64);
    }
    float n1 = fmaxf(sqrtf(ss1), 1e-12f);
    float n2 = fmaxf(sqrtf(ss2), 1e-12f);
    float c1 = SC / n1, c2 = SC / n2;
    int p1 = __builtin_amdgcn_cvt_pk_fp8_f32(u.x * c1, u.y * c1, 0, false);
    int p2 = __builtin_amdgcn_cvt_pk_fp8_f32(w.x * c2, w.y * c2, 0, false);
    g1b[(size_t)row * 64 + lane] = (unsigned short)(p1 & 0xffff);
    g2b[(size_t)row * 64 + lane] = (unsigned short)(p2 & 0xffff);
    if (lane == 0) d12[row] = 5.f * s12 / (n1 * n2);
}

// Gram exp2-sum. z=0: g1.g1 -> r11 ; z=1: g1.g2 -> r12 rows + c12 cols ;
// z=2: g2.g2 -> r22. Block 256 thr (4 waves); 128x128 tile per iter; wave
// tile 64x64 = 2 A-strips x 2 B-cols. A in regs (K=128 fp8 = 32 VGPRs).
// Y streams through 16KB LDS, 8B-fragment XOR swizzle, register prefetch.
// Symmetric passes: tiles (i,(i+d)%64) d=0..31 all i, plus d=32 for i<32 —
// each unordered strip pair exactly once; off-diag tiles emit col sums too.
__global__ __launch_bounds__(256, 2) void gram_mfma_kernel(
    const unsigned char* __restrict__ g1b, const unsigned char* __restrict__ g2b,
    float* __restrict__ r11, float* __restrict__ r12,
    float* __restrict__ c12, float* __restrict__ r22, int N)
{
    const int z = blockIdx.z;
    const bool SYM = (z != 1);
    const unsigned char* X; const unsigned char* Y; float* rrow;
    if (z == 0)      { X = g1b; Y = g1b; rrow = r11; }
    else if (z == 1) { X = g1b; Y = g2b; rrow = r12; }
    else             { X = g2b; Y = g2b; rrow = r22; }
    float* ctgt = SYM ? rrow : c12;

    const int iTile = blockIdx.x;
    int nT, dBase = 0;
    if (SYM) {
        if (blockIdx.y < 4)                     { nT = 8; dBase = blockIdx.y * 8; }
        else if (blockIdx.y == 4 && iTile < 32) { nT = 1; dBase = 32; }
        else return;
    } else {
        nT = 8;
    }

    __shared__ long Ys[128 * 16];   // 16 KB: 128 rows x 16 8B-fragments

    const int tx   = threadIdx.x;
    const int lane = tx & 63;
    const int l32  = lane & 31, lhi = lane >> 5;
    const int wi   = (tx >> 6) >> 1, wj = (tx >> 6) & 1;
    const int iBase = iTile * 128;

    // A-fragments: a[st][ks], rows iBase + wi*64 + st*32 + l32, k = ks*16+lhi*8
    long a[2][8];
#pragma unroll
    for (int st = 0; st < 2; ++st) {
        const unsigned char* xp =
            X + (size_t)(iBase + wi * 64 + st * 32 + l32) * D + lhi * 8;
#pragma unroll
        for (int ks = 0; ks < 8; ++ks)
            a[st][ks] = *(const long*)(xp + ks * 16);
    }

    float racc0[16], racc1[16];
#pragma unroll
    for (int r = 0; r < 16; ++r) { racc0[r] = 0.f; racc1[r] = 0.f; }

    auto jTileOf = [&](int t) {
        return SYM ? ((iTile + dBase + t) & 63) : ((int)blockIdx.y * 8 + t);
    };

    // prefetch first Y tile: 256 thr x 16 B x 4 = 16 KB
    long2 v[4];
    {
        const long2* yp = (const long2*)(Y + (size_t)jTileOf(0) * 128 * D);
#pragma unroll
        for (int i = 0; i < 4; ++i) v[i] = yp[i * 256 + tx];
    }

    const int j0 = wj * 64 + l32;       // B col for ct=0
    const int j1 = j0 + 32;             // B col for ct=1
    const int sw0 = j0 & 15, sw1 = j1 & 15;

    for (int t = 0; t < nT; ++t) {
        __syncthreads();   // prev iter's ds_reads done
#pragma unroll
        for (int i = 0; i < 4; ++i) {
            int chunk = i * 256 + tx;
            int j = chunk >> 3, c = chunk & 7;
            int f0p = (2 * c) ^ (j & 15);
            int base = f0p & ~1;
            long2 w = v[i];
            if (j & 1) { long tmp = w.x; w.x = w.y; w.y = tmp; }
            *(long2*)&Ys[j * 16 + base] = w;
        }
        __syncthreads();

        // prefetch next tile; flies under MFMA + epilogue
        if (t + 1 < nT) {
            const long2* yp = (const long2*)(Y + (size_t)jTileOf(t + 1) * 128 * D);
#pragma unroll
            for (int i = 0; i < 4; ++i) v[i] = yp[i * 256 + tx];
        }

        f32x16 acc00, acc01, acc10, acc11;
#pragma unroll
        for (int r = 0; r < 16; ++r) {
            acc00[r] = 0.f; acc01[r] = 0.f; acc10[r] = 0.f; acc11[r] = 0.f;
        }

#pragma unroll
        for (int ks = 0; ks < 8; ++ks) {
            int f = 2 * ks + lhi;
            long b0 = Ys[j0 * 16 + (f ^ sw0)];
            long b1 = Ys[j1 * 16 + (f ^ sw1)];
            acc00 = __builtin_amdgcn_mfma_f32_32x32x16_fp8_fp8(a[0][ks], b0, acc00, 0, 0, 0);
            acc10 = __builtin_amdgcn_mfma_f32_32x32x16_fp8_fp8(a[1][ks], b0, acc10, 0, 0, 0);
            acc01 = __builtin_amdgcn_mfma_f32_32x32x16_fp8_fp8(a[0][ks], b1, acc01, 0, 0, 0);
            acc11 = __builtin_amdgcn_mfma_f32_32x32x16_fp8_fp8(a[1][ks], b1, acc11, 0, 0, 0);
        }

        // epilogue: exp2 + row sums; col sums for cross pass and off-diag SYM
        const bool doCols = !SYM || (dBase + t) != 0;
        if (doCols) {
            const int jBase = jTileOf(t) * 128;
            float cp0 = 0.f, cp1 = 0.f;
#pragma unroll
            for (int r = 0; r < 16; ++r) {
                float e00 = __builtin_amdgcn_exp2f(acc00[r]);
                float e01 = __builtin_amdgcn_exp2f(acc01[r]);
                float e10 = __builtin_amdgcn_exp2f(acc10[r]);
                float e11 = __builtin_amdgcn_exp2f(acc11[r]);
                racc0[r] += e00 + e01;
                racc1[r] += e10 + e11;
                cp0 += e00 + e10;
                cp1 += e01 + e11;
            }
            cp0 += __shfl_xor(cp0, 32, 64);   // merge lhi halves
            cp1 += __shfl_xor(cp1, 32, 64);
            if (lane < 32) {
                atomicAdd(&ctgt[jBase + j0], cp0);
                atomicAdd(&ctgt[jBase + j1], cp1);
            }
        } else {
#pragma unroll
            for (int r = 0; r < 16; ++r) {
                racc0[r] += __builtin_amdgcn_exp2f(acc00[r]) +
                            __builtin_amdgcn_exp2f(acc01[r]);
                racc1[r] += __builtin_amdgcn_exp2f(acc10[r]) +
                            __builtin_amdgcn_exp2f(acc11[r]);
            }
        }
    }

    // row sums: reduce over 32 col-lanes; C layout row=(r&3)+8*(r>>2)+4*lhi
#pragma unroll
    for (int r = 0; r < 16; ++r) {
        float s0 = racc0[r], s1 = racc1[r];
#pragma unroll
        for (int off = 1; off < 32; off <<= 1) {
            s0 += __shfl_xor(s0, off, 64);
            s1 += __shfl_xor(s1, off, 64);
        }
        if (l32 == 0) {
            int rowm = (r & 3) + 8 * (r >> 2) + 4 * lhi;
            atomicAdd(&rrow[iBase + wi * 64 + rowm], s0);
            atomicAdd(&rrow[iBase + wi * 64 + 32 + rowm], s1);
        }
    }
}

// loss_i = 0.5*(log(r11+r12-e5) + log(r22+c12-e5)) - d12 ; out = mean
__global__ __launch_bounds__(256) void loss_reduce_kernel(
    const float* __restrict__ r11, const float* __restrict__ r12,
    const float* __restrict__ c12, const float* __restrict__ r22,
    const float* __restrict__ d12, float* __restrict__ out, int N)
{
    __shared__ float sm[256];
    float s = 0.f;
    for (int i = blockIdx.x * 256 + threadIdx.x; i < N; i += gridDim.x * 256) {
        float neg1 = r11[i] + r12[i] - E5;
        float neg2 = r22[i] + c12[i] - E5;
        s += 0.5f * (logf(neg1) + logf(neg2)) - d12[i];
    }
    sm[threadIdx.x] = s;
    __syncthreads();
    for (int w = 128; w > 0; w >>= 1) {
        if (threadIdx.x < w) sm[threadIdx.x] += sm[threadIdx.x + w];
        __syncthreads();
    }
    if (threadIdx.x == 0) atomicAdd(out, sm[0] / (float)N);
}

extern "C" void kernel_launch(void* const* d_in, const int* in_sizes, int n_in,
                              void* d_out, int out_size, void* d_ws, size_t ws_size,
                              hipStream_t stream) {
    const float* h1 = (const float*)d_in[0];
    const float* h2 = (const float*)d_in[1];
    const int N = in_sizes[0] / D;   // 8192

    unsigned char* g1b = (unsigned char*)d_ws;
    unsigned char* g2b = g1b + (size_t)N * D;
    float* acc  = (float*)(g2b + (size_t)N * D);
    float* r11  = acc;
    float* r12  = acc + N;
    float* c12  = acc + 2 * N;
    float* r22  = acc + 3 * N;
    float* d12  = acc + 4 * N;
    float* out  = (float*)d_out;

    normalize_kernel<<<N / 4, 256, 0, stream>>>(
        (const float2*)h1, (const float2*)h2,
        (unsigned short*)g1b, (unsigned short*)g2b, d12, acc, out, N);

    dim3 grid(N / 128, 8, 3);
    gram_mfma_kernel<<<grid, 256, 0, stream>>>(g1b, g2b, r11, r12, c12, r22, N);

    loss_reduce_kernel<<<32, 256, 0, stream>>>(r11, r12, c12, r22, d12, out, N);
}